// Round 1
// baseline (54286.035 us; speedup 1.0000x reference)
//
#include <hip/hip_runtime.h>

// Problem constants
#define HH 512
#define BB 128
#define TT 512
#define LL 4
#define JJ 2

typedef _Float16 f16;
typedef __attribute__((ext_vector_type(4))) _Float16 f16x4;
typedef __attribute__((ext_vector_type(8))) _Float16 f16x8;
typedef __attribute__((ext_vector_type(4))) float f32x4;

// ---------------------------------------------------------------------------
// Per-cell parameter blocks (passed by value; <=4 cells per diagonal, stage2
// has 2 GEMMs (g0,g1) per cell -> up to 8 slots).
// ---------------------------------------------------------------------------
struct S1Cell {
    const float* h0;   // A low half source (k<512), fp32, row stride h0s
    const float* h1;   // A high half source (k>=512), fp32, row stride h1s
    const f16*   wT;   // lin weights transposed: [2048][1024] (N x K)
    const float* bias; // lin_b [2048]
    float* z0;         // [128][512]
    float* z1;         // [128][512]
    f16*   A0;         // [128][1024] = [h0 | h1*r]
    f16*   A1;         // [128][1024] = [h1 | h0*q]
    int h0s, h1s;
};
struct S1Params { S1Cell c[4]; };

struct S2Cell {
    const f16*   A;    // [128][1024] fp16
    const f16*   wT;   // [512][1024] (N x K)
    const float* bias; // [512]
    const float* z;    // gate for this output: [128][512]
    const float* oldp; // old state, row stride olds
    float*       dst;  // new state, row stride dsts
    int olds, dsts;
};
struct S2Params { S2Cell c[8]; };

// ---------------------------------------------------------------------------
// Weight convert + transpose: src fp32 [mat][K][N] -> dst fp16 [mat][N][K]
// ---------------------------------------------------------------------------
__global__ __launch_bounds__(256) void wt_transpose_cvt(
    const float* __restrict__ src, f16* __restrict__ dst, int K, int N)
{
    __shared__ f16 tile[32][33];
    const size_t mat = blockIdx.z;
    const float* s = src + mat * (size_t)K * N;
    f16* d = dst + mat * (size_t)K * N;
    const int k0 = blockIdx.x * 32, n0 = blockIdx.y * 32;
    const int tx = threadIdx.x & 31, ty = threadIdx.x >> 5; // 32 x 8
#pragma unroll
    for (int i = 0; i < 4; i++) {
        int k = k0 + ty + 8 * i;
        tile[ty + 8 * i][tx] = (f16)s[(size_t)k * N + n0 + tx];
    }
    __syncthreads();
#pragma unroll
    for (int i = 0; i < 4; i++) {
        int n = n0 + ty + 8 * i;
        d[(size_t)n * K + k0 + tx] = tile[tx][ty + 8 * i];
    }
}

// ---------------------------------------------------------------------------
// Stage 1: g = sigmoid([h0|h1] @ lin_w + lin_b)   (M=128, K=1024, N=2048)
// Tile: 128x64, BK=64, 4 waves (2x2), 16x16x32 f16 MFMA.
// Epilogue by column class (512-wide, block-uniform since BN=64):
//   cls0: z0 = s; A0[:, n]      = f16(h0[:, n])
//   cls1: z1 = s; A1[:, n]      = f16(h1[:, n])
//   cls2:         A0[:, 512+n]  = f16(h1[:, n] * s)   (r)
//   cls3:         A1[:, 512+n]  = f16(h0[:, n] * s)   (q)
// ---------------------------------------------------------------------------
__global__ __launch_bounds__(256) void stage1_kernel(S1Params P)
{
    const S1Cell c = P.c[blockIdx.y];
    const int n0 = blockIdx.x * 64;

    __shared__ __attribute__((aligned(16))) f16 Al[128][72]; // +8 pad: 2-way max
    __shared__ __attribute__((aligned(16))) f16 Bl[64][72];

    const int tid  = threadIdx.x;
    const int lane = tid & 63;
    const int wid  = tid >> 6;
    const int wm   = wid & 1;   // M half (64 rows)
    const int wn   = wid >> 1;  // N half (32 cols)

    f32x4 acc[4][2] = {};

    const int acg = tid & 15;   // A k-group: 4 floats each -> 64 k
    const int ar  = tid >> 4;   // A row base (16), x8 iters = 128 rows
    const int bkc = tid & 7;    // B k-group: 8 halves -> 64 k
    const int bnr = tid >> 3;   // B n base (32), x2 iters = 64 rows

    for (int k0 = 0; k0 < 1024; k0 += 64) {
        // --- A tile: fp32 -> fp16, source is h0 (k<512) or h1 (k>=512)
        int kk = k0 + acg * 4;
        const float* asrc; int ast;
        if (kk < 512) { asrc = c.h0; ast = c.h0s; }
        else          { asrc = c.h1; ast = c.h1s; kk -= 512; }
#pragma unroll
        for (int i = 0; i < 8; i++) {
            int rr = ar + 16 * i;
            float4 v = *(const float4*)(asrc + (size_t)rr * ast + kk);
            f16x4 h; h[0] = (f16)v.x; h[1] = (f16)v.y; h[2] = (f16)v.z; h[3] = (f16)v.w;
            *(f16x4*)(&Al[rr][acg * 4]) = h;
        }
        // --- B tile: W^T rows are K-contiguous fp16, 16B vector both sides
#pragma unroll
        for (int i = 0; i < 2; i++) {
            int nn = bnr + 32 * i;
            f16x8 v = *(const f16x8*)(c.wT + (size_t)(n0 + nn) * 1024 + k0 + bkc * 8);
            *(f16x8*)(&Bl[nn][bkc * 8]) = v;
        }
        __syncthreads();
#pragma unroll
        for (int ks = 0; ks < 64; ks += 32) {
            const int kl = ks + (lane >> 4) * 8;
            f16x8 af[4], bf[2];
#pragma unroll
            for (int fm = 0; fm < 4; fm++)
                af[fm] = *(const f16x8*)(&Al[wm * 64 + fm * 16 + (lane & 15)][kl]);
#pragma unroll
            for (int fn = 0; fn < 2; fn++)
                bf[fn] = *(const f16x8*)(&Bl[wn * 32 + fn * 16 + (lane & 15)][kl]);
#pragma unroll
            for (int fm = 0; fm < 4; fm++)
#pragma unroll
                for (int fn = 0; fn < 2; fn++)
                    acc[fm][fn] = __builtin_amdgcn_mfma_f32_16x16x32_f16(
                        af[fm], bf[fn], acc[fm][fn], 0, 0, 0);
        }
        __syncthreads();
    }

    const int cls = n0 >> 9;
#pragma unroll
    for (int fm = 0; fm < 4; fm++) {
#pragma unroll
        for (int fn = 0; fn < 2; fn++) {
#pragma unroll
            for (int r = 0; r < 4; r++) {
                int m = wm * 64 + fm * 16 + (lane >> 4) * 4 + r;
                int n = n0 + wn * 32 + fn * 16 + (lane & 15);
                float x = acc[fm][fn][r] + c.bias[n];
                float s = 1.0f / (1.0f + __expf(-x));
                int nn = n & 511;
                if (cls == 0) {
                    c.z0[m * 512 + nn] = s;
                    c.A0[m * 1024 + nn] = (f16)c.h0[(size_t)m * c.h0s + nn];
                } else if (cls == 1) {
                    c.z1[m * 512 + nn] = s;
                    c.A1[m * 1024 + nn] = (f16)c.h1[(size_t)m * c.h1s + nn];
                } else if (cls == 2) {
                    c.A0[m * 1024 + 512 + nn] = (f16)(c.h1[(size_t)m * c.h1s + nn] * s);
                } else {
                    c.A1[m * 1024 + 512 + nn] = (f16)(c.h0[(size_t)m * c.h0s + nn] * s);
                }
            }
        }
    }
}

// ---------------------------------------------------------------------------
// Stage 2: hc = tanh(A @ gw + gb); dst = z*hc + (1-z)*old
// (g0 produces h0_cap -> new h1 uses z1; g1 produces h1_cap -> new h0 uses z0;
//  the host wires z/old/dst per slot, math is identical.)
// Tile: 128x32, BK=64, 4 waves (2x2).
// ---------------------------------------------------------------------------
__global__ __launch_bounds__(256) void stage2_kernel(S2Params P)
{
    const S2Cell c = P.c[blockIdx.y];
    const int n0 = blockIdx.x * 32;

    __shared__ __attribute__((aligned(16))) f16 Al[128][72];
    __shared__ __attribute__((aligned(16))) f16 Bl[32][72];

    const int tid  = threadIdx.x;
    const int lane = tid & 63;
    const int wid  = tid >> 6;
    const int wm   = wid & 1;
    const int wn   = wid >> 1;  // 16-col half

    f32x4 acc[4] = {};
    const int kc = tid & 7;     // 8 x 8 halves = 64 k
    const int rb = tid >> 3;    // 32 rows base

    for (int k0 = 0; k0 < 1024; k0 += 64) {
#pragma unroll
        for (int i = 0; i < 4; i++) {
            int rr = rb + 32 * i;
            f16x8 v = *(const f16x8*)(c.A + (size_t)rr * 1024 + k0 + kc * 8);
            *(f16x8*)(&Al[rr][kc * 8]) = v;
        }
        {
            f16x8 v = *(const f16x8*)(c.wT + (size_t)(n0 + rb) * 1024 + k0 + kc * 8);
            *(f16x8*)(&Bl[rb][kc * 8]) = v;
        }
        __syncthreads();
#pragma unroll
        for (int ks = 0; ks < 64; ks += 32) {
            const int kl = ks + (lane >> 4) * 8;
            f16x8 bf = *(const f16x8*)(&Bl[wn * 16 + (lane & 15)][kl]);
#pragma unroll
            for (int fm = 0; fm < 4; fm++) {
                f16x8 af = *(const f16x8*)(&Al[wm * 64 + fm * 16 + (lane & 15)][kl]);
                acc[fm] = __builtin_amdgcn_mfma_f32_16x16x32_f16(af, bf, acc[fm], 0, 0, 0);
            }
        }
        __syncthreads();
    }

#pragma unroll
    for (int fm = 0; fm < 4; fm++) {
#pragma unroll
        for (int r = 0; r < 4; r++) {
            int m = wm * 64 + fm * 16 + (lane >> 4) * 4 + r;
            int n = n0 + wn * 16 + (lane & 15);
            float hc  = tanhf(acc[fm][r] + c.bias[n]);
            float zv  = c.z[m * 512 + n];
            float old = c.oldp[(size_t)m * c.olds + n];
            c.dst[(size_t)m * c.dsts + n] = zv * hc + (1.0f - zv) * old;
        }
    }
}

// ---------------------------------------------------------------------------
// Host side: wavefront over anti-diagonals d = t + l. Cells on a diagonal are
// independent (deps: (t,l-1) and (t-1,l), both on d-1) -> batch up to 4 cells
// per launch; kernel boundaries are the device-wide sync.
// h0 flows through a parity-double-buffered pipe; h1[l] lives in d_out's
// H1_final region (memset to 0 each call).
// ---------------------------------------------------------------------------
extern "C" void kernel_launch(void* const* d_in, const int* in_sizes, int n_in,
                              void* d_out, int out_size, void* d_ws, size_t ws_size,
                              hipStream_t stream)
{
    (void)in_sizes; (void)n_in; (void)out_size; (void)ws_size;

    const float* H0in  = (const float*)d_in[0];
    const float* lin_w = (const float*)d_in[1];
    const float* lin_b = (const float*)d_in[2];
    const float* g0_w  = (const float*)d_in[3];
    const float* g0_b  = (const float*)d_in[4];
    const float* g1_w  = (const float*)d_in[5];
    const float* g1_b  = (const float*)d_in[6];

    float* H0out = (float*)d_out;                       // (B,T,H)
    float* H1st  = H0out + (size_t)BB * TT * HH;        // (B,L,H): state lives here

    // Workspace layout (~56 MB)
    char* p = (char*)d_ws;
    f16* linT = (f16*)p; p += (size_t)LL * JJ * 2048 * 1024 * sizeof(f16); // 32 MB
    f16* g0T  = (f16*)p; p += (size_t)LL * JJ * 512 * 1024 * sizeof(f16);  //  8 MB
    f16* g1T  = (f16*)p; p += (size_t)LL * JJ * 512 * 1024 * sizeof(f16);  //  8 MB
    f16* A0b  = (f16*)p; p += (size_t)LL * BB * 1024 * sizeof(f16);
    f16* A1b  = (f16*)p; p += (size_t)LL * BB * 1024 * sizeof(f16);
    float* z0b = (float*)p; p += (size_t)LL * BB * 512 * sizeof(float);
    float* z1b = (float*)p; p += (size_t)LL * BB * 512 * sizeof(float);
    float* h0m = (float*)p; p += (size_t)LL * BB * 512 * sizeof(float);
    float* h1m = (float*)p; p += (size_t)LL * BB * 512 * sizeof(float);
    float* pipe = (float*)p; p += (size_t)2 * LL * BB * 512 * sizeof(float);

    // One-time (per call) weight fp16 transposes
    wt_transpose_cvt<<<dim3(32, 64, 8), 256, 0, stream>>>(lin_w, linT, 1024, 2048);
    wt_transpose_cvt<<<dim3(32, 16, 8), 256, 0, stream>>>(g0_w,  g0T,  1024, 512);
    wt_transpose_cvt<<<dim3(32, 16, 8), 256, 0, stream>>>(g1_w,  g1T,  1024, 512);
    hipMemsetAsync(H1st, 0, (size_t)BB * LL * HH * sizeof(float), stream);

    for (int d = 0; d < TT + LL - 1; d++) {
        int lmin = d - (TT - 1); if (lmin < 0) lmin = 0;
        int lmax = d < LL - 1 ? d : LL - 1;
        int nc = lmax - lmin + 1;

        for (int j = 0; j < JJ; j++) {
            S1Params p1{};
            S2Params p2{};
            for (int ci = 0; ci < nc; ci++) {
                int l = lmin + ci, t = d - l;
                int w = l * JJ + j;
                S1Cell& s1 = p1.c[ci];
                if (j == 0) {
                    if (l == 0) { s1.h0 = H0in + (size_t)t * HH; s1.h0s = TT * HH; }
                    else        { s1.h0 = pipe + (size_t)((d & 1) * LL + l) * BB * HH; s1.h0s = HH; }
                    s1.h1 = H1st + l * HH; s1.h1s = LL * HH;
                } else {
                    s1.h0 = h0m + (size_t)l * BB * HH; s1.h0s = HH;
                    s1.h1 = h1m + (size_t)l * BB * HH; s1.h1s = HH;
                }
                s1.wT   = linT + (size_t)w * 2048 * 1024;
                s1.bias = lin_b + (size_t)w * 2048;
                s1.z0 = z0b + (size_t)l * BB * 512;
                s1.z1 = z1b + (size_t)l * BB * 512;
                s1.A0 = A0b + (size_t)l * BB * 1024;
                s1.A1 = A1b + (size_t)l * BB * 1024;

                // g0 -> h0_cap -> new h1 (gate z1, old = h1 input)
                S2Cell& a = p2.c[2 * ci];
                a.A = s1.A0; a.wT = g0T + (size_t)w * 512 * 1024; a.bias = g0_b + (size_t)w * 512;
                a.z = s1.z1; a.oldp = s1.h1; a.olds = s1.h1s;
                if (j == 0) { a.dst = h1m + (size_t)l * BB * HH; a.dsts = HH; }
                else        { a.dst = H1st + l * HH;             a.dsts = LL * HH; }

                // g1 -> h1_cap -> new h0 (gate z0, old = h0 input)
                S2Cell& b = p2.c[2 * ci + 1];
                b.A = s1.A1; b.wT = g1T + (size_t)w * 512 * 1024; b.bias = g1_b + (size_t)w * 512;
                b.z = s1.z0; b.oldp = s1.h0; b.olds = s1.h0s;
                if (j == 0) { b.dst = h0m + (size_t)l * BB * HH; b.dsts = HH; }
                else if (l == LL - 1) { b.dst = H0out + (size_t)t * HH; b.dsts = TT * HH; }
                else { b.dst = pipe + (size_t)(((d + 1) & 1) * LL + (l + 1)) * BB * HH; b.dsts = HH; }
            }
            stage1_kernel<<<dim3(32, nc), 256, 0, stream>>>(p1);
            stage2_kernel<<<dim3(16, 2 * nc), 256, 0, stream>>>(p2);
        }
    }
}